// Round 14
// baseline (166.469 us; speedup 1.0000x reference)
//
#include <hip/hip_runtime.h>
#include <hip/hip_cooperative_groups.h>

namespace cg = cooperative_groups;

#define NN 65536
#define FH 128
#define FO 16
#define NE (NN * 16)
#define EPB 4096   // edges per bucket block (NE/256)
#define BCAP 8192  // per-bucket padded capacity (mean 4096, sd 62 -> 65 sigma)

typedef unsigned short u16x8 __attribute__((ext_vector_type(8)));
typedef unsigned short u16x4 __attribute__((ext_vector_type(4)));
typedef float f32x4 __attribute__((ext_vector_type(4)));
typedef short s16x8 __attribute__((ext_vector_type(8)));

__device__ inline float b2f(unsigned short u) {
    union { unsigned int i; float f; } x;
    x.i = ((unsigned int)u) << 16;
    return x.f;
}
__device__ inline unsigned short f2bf(float f) {
    union { float f; unsigned int i; } x;
    x.f = f;
    unsigned int r = x.i + 0x7fff + ((x.i >> 16) & 1);  // RNE
    return (unsigned short)(r >> 16);
}

// ============ cooperative CSR build: init + bucket-partition + bucket-sort ============
// 256 blocks x 256 threads, 2 grid syncs
__global__ __launch_bounds__(256) void build_csr(const int* __restrict__ eu,
                                                 const int* __restrict__ ev,
                                                 int* __restrict__ cursors,
                                                 unsigned int* __restrict__ tmp,
                                                 unsigned short* __restrict__ evw16,
                                                 int* __restrict__ row_start,
                                                 int* __restrict__ deg,
                                                 float* __restrict__ isd) {
    __shared__ int lhist[256];
    __shared__ int lbase[256];
    __shared__ int loff[256];
    __shared__ int lscan[256];
    __shared__ int lcur[256];
    __shared__ unsigned int lrec[BCAP];     // 32KB record cache
    __shared__ unsigned short lbuf[BCAP];   // 16KB sorted v16
    cg::grid_group grid = cg::this_grid();
    const int b = blockIdx.x;
    const int tid = threadIdx.x;

    // ---- phase 0: init own bucket cursor ----
    if (tid == 0) cursors[b] = b * BCAP;
    grid.sync();

    // ---- phase 1: partition my edge chunk into 256 padded buckets by u>>8 ----
    lhist[tid] = 0;
    loff[tid] = 0;
    __syncthreads();
    const int e0 = b * EPB;
    int us[16], vs[16];
#pragma unroll
    for (int k = 0; k < 16; ++k) {
        int e = e0 + k * 256 + tid;
        us[k] = eu[e];
        vs[k] = ev[e];
        atomicAdd(&lhist[us[k] >> 8], 1);
    }
    __syncthreads();
    lbase[tid] = atomicAdd(&cursors[tid], lhist[tid]);
    __syncthreads();
#pragma unroll
    for (int k = 0; k < 16; ++k) {
        int bk = us[k] >> 8;
        int pos = lbase[bk] + atomicAdd(&loff[bk], 1);
        tmp[pos] = (((unsigned int)(us[k] & 255)) << 16) | (unsigned int)vs[k];
    }
    grid.sync();

    // ---- phase 2: per-bucket degree count + scan + CSR sort (records cached in LDS) ----
    const int base = b * BCAP;
    const int count = cursors[b] - base;
    lhist[tid] = 0;  // reuse as lcnt
    __syncthreads();
    for (int i = tid; i < count; i += 256) {
        unsigned int rec = tmp[base + i];
        lrec[i] = rec;
        atomicAdd(&lhist[rec >> 16], 1);
    }
    __syncthreads();
    const int c = lhist[tid];
    lscan[tid] = c;
    __syncthreads();
    for (int off = 1; off < 256; off <<= 1) {
        int v = (tid >= off) ? lscan[tid - off] : 0;
        __syncthreads();
        lscan[tid] += v;
        __syncthreads();
    }
    const int myStart = lscan[tid] - c;  // exclusive scan
    lcur[tid] = myStart;
    const int node = b * 256 + tid;
    row_start[node] = base + myStart;
    deg[node] = c;
    isd[node] = (c > 0) ? (1.0f / sqrtf((float)c)) : 0.0f;
    __syncthreads();
    for (int i = tid; i < count; i += 256) {
        unsigned int rec = lrec[i];
        int off = atomicAdd(&lcur[rec >> 16], 1);
        lbuf[off] = (unsigned short)(rec & 0xFFFFu);
    }
    __syncthreads();
    for (int i = tid; i < count; i += 256) {
        evw16[base + i] = lbuf[i];
    }
}

// ============ GEMM1 (MFMA): t1s = bf16(isd[row] * (x @ W1)) ============
// A-frags loaded straight from global f32 (x rows have no intra-block reuse)
__global__ __launch_bounds__(256) void gemm1_mfma(const float* __restrict__ x,
                                                  const float* __restrict__ W1,
                                                  const float* __restrict__ isd,
                                                  unsigned short* __restrict__ t1s) {
    __shared__ unsigned short wsT[128][136];  // wsT[c][k] = bf16(W1[k][c])
    const int tid = threadIdx.x;
    const int row0 = blockIdx.x * 64;
    {
        const int c0 = (tid & 31) * 4;
        const int kr = tid >> 5;
        for (int kk = 0; kk < 16; ++kk) {
            int k = kk * 8 + kr;
            float4 v = *(const float4*)&W1[(size_t)k * 128 + c0];
            wsT[c0 + 0][k] = f2bf(v.x);
            wsT[c0 + 1][k] = f2bf(v.y);
            wsT[c0 + 2][k] = f2bf(v.z);
            wsT[c0 + 3][k] = f2bf(v.w);
        }
    }
    const int lane = tid & 63;
    const int w = tid >> 6;
    const int ar = row0 + w * 16 + (lane & 15);  // A row (global)
    const int k0 = (lane >> 4) * 8;
    s16x8 afrag[4];
#pragma unroll
    for (int kk = 0; kk < 4; ++kk) {
        float4 va = *(const float4*)&x[(size_t)ar * 128 + kk * 32 + k0];
        float4 vb = *(const float4*)&x[(size_t)ar * 128 + kk * 32 + k0 + 4];
        u16x8 t;
        t[0] = f2bf(va.x); t[1] = f2bf(va.y); t[2] = f2bf(va.z); t[3] = f2bf(va.w);
        t[4] = f2bf(vb.x); t[5] = f2bf(vb.y); t[6] = f2bf(vb.z); t[7] = f2bf(vb.w);
        afrag[kk] = *(s16x8*)&t;
    }
    __syncthreads();
    f32x4 acc[8];
#pragma unroll
    for (int n = 0; n < 8; ++n) acc[n] = (f32x4){0.f, 0.f, 0.f, 0.f};
#pragma unroll
    for (int n = 0; n < 8; ++n) {
        const int bc = n * 16 + (lane & 15);
#pragma unroll
        for (int kk = 0; kk < 4; ++kk) {
            s16x8 bfrag = *(const s16x8*)&wsT[bc][kk * 32 + k0];
            acc[n] = __builtin_amdgcn_mfma_f32_16x16x32_bf16(afrag[kk], bfrag, acc[n], 0, 0, 0);
        }
    }
    const int orow = row0 + w * 16 + (lane >> 4) * 4;
    const float s0 = isd[orow + 0];
    const float s1 = isd[orow + 1];
    const float s2 = isd[orow + 2];
    const float s3 = isd[orow + 3];
#pragma unroll
    for (int n = 0; n < 8; ++n) {
        const int col = n * 16 + (lane & 15);
        t1s[(size_t)(orow + 0) * 128 + col] = f2bf(s0 * acc[n][0]);
        t1s[(size_t)(orow + 1) * 128 + col] = f2bf(s1 * acc[n][1]);
        t1s[(size_t)(orow + 2) * 128 + col] = f2bf(s2 * acc[n][2]);
        t1s[(size_t)(orow + 3) * 128 + col] = f2bf(s3 * acc[n][3]);
    }
}

// ============ FUSED layer-1 aggregate + relu + GEMM2 (natural node order) ============
__global__ __launch_bounds__(256) void fused_agg_gemm2(const int* __restrict__ row_start,
                                                       const int* __restrict__ deg,
                                                       const unsigned short* __restrict__ evw16,
                                                       const float* __restrict__ isd,
                                                       const unsigned short* __restrict__ src,
                                                       const float* __restrict__ W2,
                                                       float* __restrict__ t2s) {
    __shared__ unsigned short hs[16][136];  // bf16 h tile
    __shared__ float w2T[16][132];          // w2T[c][k] = W2[k][c]
    const int tid = threadIdx.x;
    for (int i = tid; i < 128 * 16; i += 256) {
        int k = i >> 4, cc = i & 15;
        w2T[cc][k] = W2[i];
    }
    const int slot = tid >> 4;
    const int node = blockIdx.x * 16 + slot;
    const int c0 = (tid & 15) * 8;
    const int rs = row_start[node];
    const int re = rs + deg[node];
    const float s = isd[node];
    float acc[8] = {};
    int p = rs;
    const int e4 = rs + ((re - rs) & ~3);
    for (; p < e4; p += 4) {
        int v0 = evw16[p];
        int v1 = evw16[p + 1];
        int v2 = evw16[p + 2];
        int v3 = evw16[p + 3];
        u16x8 a0 = *(const u16x8*)&src[(size_t)v0 * 128 + c0];
        u16x8 a1 = *(const u16x8*)&src[(size_t)v1 * 128 + c0];
        u16x8 a2 = *(const u16x8*)&src[(size_t)v2 * 128 + c0];
        u16x8 a3 = *(const u16x8*)&src[(size_t)v3 * 128 + c0];
#pragma unroll
        for (int j = 0; j < 8; ++j)
            acc[j] += (b2f(a0[j]) + b2f(a1[j])) + (b2f(a2[j]) + b2f(a3[j]));
    }
    for (; p < re; ++p) {
        int v0 = evw16[p];
        u16x8 a = *(const u16x8*)&src[(size_t)v0 * 128 + c0];
#pragma unroll
        for (int j = 0; j < 8; ++j) acc[j] += b2f(a[j]);
    }
    u16x8 o;
#pragma unroll
    for (int j = 0; j < 8; ++j) o[j] = f2bf(fmaxf(s * acc[j], 0.f));
    *(u16x8*)&hs[slot][c0] = o;
    __syncthreads();
    // phase 2: thread (slot, tx) computes t2s[node][tx]
    const int tx = tid & 15;
    float acc2 = 0.f;
#pragma unroll
    for (int k = 0; k < 128; k += 8) {
        u16x8 hv = *(const u16x8*)&hs[slot][k];
#pragma unroll
        for (int j = 0; j < 8; ++j) acc2 += b2f(hv[j]) * w2T[tx][k + j];
    }
    t2s[(size_t)node * 16 + tx] = s * acc2;
}

// ============ gather F=16: out[n] = isd[n] * sum t2s[v] (natural order) ============
__global__ __launch_bounds__(256) void spmm_gather16f(const int* __restrict__ row_start,
                                                      const int* __restrict__ deg,
                                                      const unsigned short* __restrict__ evw16,
                                                      const float* __restrict__ isd,
                                                      const float* __restrict__ t2s,
                                                      float* __restrict__ out) {
    const int node = blockIdx.x * 64 + (threadIdx.x >> 2);
    const int j = (threadIdx.x & 3) * 4;
    const int rs = row_start[node];
    const int re = rs + deg[node];
    const float s = isd[node];
    float4 acc = {0.f, 0.f, 0.f, 0.f};
    int p = rs;
    const int e4 = rs + ((re - rs) & ~3);
    for (; p < e4; p += 4) {
        int v0 = evw16[p];
        int v1 = evw16[p + 1];
        int v2 = evw16[p + 2];
        int v3 = evw16[p + 3];
        float4 a0 = *(const float4*)&t2s[(size_t)v0 * 16 + j];
        float4 a1 = *(const float4*)&t2s[(size_t)v1 * 16 + j];
        float4 a2 = *(const float4*)&t2s[(size_t)v2 * 16 + j];
        float4 a3 = *(const float4*)&t2s[(size_t)v3 * 16 + j];
        acc.x += (a0.x + a1.x) + (a2.x + a3.x);
        acc.y += (a0.y + a1.y) + (a2.y + a3.y);
        acc.z += (a0.z + a1.z) + (a2.z + a3.z);
        acc.w += (a0.w + a1.w) + (a2.w + a3.w);
    }
    for (; p < re; ++p) {
        int v = evw16[p];
        float4 a = *(const float4*)&t2s[(size_t)v * 16 + j];
        acc.x += a.x;
        acc.y += a.y;
        acc.z += a.z;
        acc.w += a.w;
    }
    float4 o;
    o.x = s * acc.x;
    o.y = s * acc.y;
    o.z = s * acc.z;
    o.w = s * acc.w;
    *(float4*)&out[(size_t)node * 16 + j] = o;
}

extern "C" void kernel_launch(void* const* d_in, const int* in_sizes, int n_in,
                              void* d_out, int out_size, void* d_ws, size_t ws_size,
                              hipStream_t stream) {
    const float* x  = (const float*)d_in[0];
    const int*   eu = (const int*)d_in[1];
    const int*   ev = (const int*)d_in[2];
    // d_in[3] (edge_weight) unused: recomputed separably from degrees
    const float* W1 = (const float*)d_in[4];
    const float* W2 = (const float*)d_in[5];
    float* out = (float*)d_out;

    // workspace layout (16B-aligned carve-outs)
    char* p = (char*)d_ws;
    int* row_start        = (int*)p;            p += (size_t)NN * 4;            // 256KB
    int* deg              = (int*)p;            p += (size_t)NN * 4;            // 256KB
    float* isd            = (float*)p;          p += (size_t)NN * 4;            // 256KB
    int* cursors          = (int*)p;            p += 4096;                      // 1KB used
    unsigned int* tmp     = (unsigned int*)p;   p += (size_t)256 * BCAP * 4;    // 8MB
    unsigned short* evw16 = (unsigned short*)p; p += (size_t)256 * BCAP * 2;    // 4MB
    unsigned short* t1s   = (unsigned short*)p; p += (size_t)NN * FH * 2;       // 16MB
    float* t2s            = (float*)p;                                          // 4MB

    // cooperative CSR build (init + partition + sort, 2 grid syncs)
    {
        void* args[] = {(void*)&eu, (void*)&ev, (void*)&cursors, (void*)&tmp,
                        (void*)&evw16, (void*)&row_start, (void*)&deg, (void*)&isd};
        hipLaunchCooperativeKernel((const void*)build_csr, dim3(256), dim3(256),
                                   args, 0, stream);
    }

    // layer 1: t1s = bf16(isd * (x @ W1))
    gemm1_mfma<<<NN / 64, 256, 0, stream>>>(x, W1, isd, t1s);

    // fused: h = relu(isd * gather(t1s)) ; t2s = isd * (h @ W2)
    fused_agg_gemm2<<<NN / 16, 256, 0, stream>>>(row_start, deg, evw16, isd, t1s, W2, t2s);

    // out = isd * gather(t2s)
    spmm_gather16f<<<NN / 64, 256, 0, stream>>>(row_start, deg, evw16, isd, t2s, out);
}

// Round 15
// 101.012 us; speedup vs baseline: 1.6480x; 1.6480x over previous
//
#include <hip/hip_runtime.h>

#define NN 65536
#define FH 128
#define FO 16
#define NE (NN * 16)
#define EPB 4096   // edges per bucketA block
#define BCAP 8192  // per-bucket padded capacity (mean 4096, sd 62 -> 65 sigma)

typedef unsigned short u16x8 __attribute__((ext_vector_type(8)));
typedef unsigned short u16x4 __attribute__((ext_vector_type(4)));
typedef float f32x4 __attribute__((ext_vector_type(4)));
typedef short s16x8 __attribute__((ext_vector_type(8)));

__device__ inline float b2f(unsigned short u) {
    union { unsigned int i; float f; } x;
    x.i = ((unsigned int)u) << 16;
    return x.f;
}
__device__ inline unsigned short f2bf(float f) {
    union { float f; unsigned int i; } x;
    x.f = f;
    unsigned int r = x.i + 0x7fff + ((x.i >> 16) & 1);  // RNE
    return (unsigned short)(r >> 16);
}

// ============ init: per-bucket cursors to padded bases ============
__global__ __launch_bounds__(256) void init_kernel(int* __restrict__ cursors) {
    cursors[threadIdx.x] = threadIdx.x * BCAP;
}

// ============ bucketA: partition edges into 256 padded buckets by u>>8 ============
__global__ __launch_bounds__(256) void bucketA(const int* __restrict__ eu,
                                               const int* __restrict__ ev,
                                               int* __restrict__ cursors,
                                               unsigned int* __restrict__ tmp) {
    __shared__ int lhist[256];
    __shared__ int lbase[256];
    __shared__ int loff[256];
    const int tid = threadIdx.x;
    lhist[tid] = 0;
    loff[tid] = 0;
    __syncthreads();
    const int e0 = blockIdx.x * EPB;
    int us[16], vs[16];
#pragma unroll
    for (int k = 0; k < 16; ++k) {
        int e = e0 + k * 256 + tid;
        us[k] = eu[e];
        vs[k] = ev[e];
        atomicAdd(&lhist[us[k] >> 8], 1);
    }
    __syncthreads();
    lbase[tid] = atomicAdd(&cursors[tid], lhist[tid]);
    __syncthreads();
#pragma unroll
    for (int k = 0; k < 16; ++k) {
        int b = us[k] >> 8;
        int pos = lbase[b] + atomicAdd(&loff[b], 1);
        tmp[pos] = (((unsigned int)(us[k] & 255)) << 16) | (unsigned int)vs[k];
    }
}

// ============ bucketB: per-bucket degree count + scan + CSR sort (LDS) ============
__global__ __launch_bounds__(256) void bucketB(const int* __restrict__ cursors,
                                               const unsigned int* __restrict__ tmp,
                                               unsigned short* __restrict__ evw16,
                                               int* __restrict__ row_start,
                                               int* __restrict__ deg,
                                               float* __restrict__ isd) {
    __shared__ int lcnt[256];
    __shared__ int lscan[256];
    __shared__ int lcur[256];
    __shared__ unsigned short lbuf[BCAP];
    const int b = blockIdx.x;
    const int tid = threadIdx.x;
    const int base = b * BCAP;
    const int count = cursors[b] - base;
    lcnt[tid] = 0;
    __syncthreads();
    for (int i = tid; i < count; i += 256) {
        atomicAdd(&lcnt[tmp[base + i] >> 16], 1);
    }
    __syncthreads();
    const int c = lcnt[tid];
    lscan[tid] = c;
    __syncthreads();
    for (int off = 1; off < 256; off <<= 1) {
        int v = (tid >= off) ? lscan[tid - off] : 0;
        __syncthreads();
        lscan[tid] += v;
        __syncthreads();
    }
    const int myStart = lscan[tid] - c;  // exclusive scan
    lcur[tid] = myStart;
    const int node = b * 256 + tid;
    row_start[node] = base + myStart;
    deg[node] = c;
    isd[node] = (c > 0) ? (1.0f / sqrtf((float)c)) : 0.0f;
    __syncthreads();
    for (int i = tid; i < count; i += 256) {
        unsigned int rec = tmp[base + i];
        int off = atomicAdd(&lcur[rec >> 16], 1);
        lbuf[off] = (unsigned short)(rec & 0xFFFFu);
    }
    __syncthreads();
    for (int i = tid; i < count; i += 256) {
        evw16[base + i] = lbuf[i];
    }
}

// ============ GEMM1 (MFMA): t1s = bf16(isd[row] * (x @ W1)) ============
__global__ __launch_bounds__(256) void gemm1_mfma(const float* __restrict__ x,
                                                  const float* __restrict__ W1,
                                                  const float* __restrict__ isd,
                                                  unsigned short* __restrict__ t1s) {
    __shared__ unsigned short wsT[128][136];  // wsT[c][k] = bf16(W1[k][c])
    const int tid = threadIdx.x;
    const int row0 = blockIdx.x * 64;
    {
        const int c0 = (tid & 31) * 4;
        const int kr = tid >> 5;
        for (int kk = 0; kk < 16; ++kk) {
            int k = kk * 8 + kr;
            float4 v = *(const float4*)&W1[(size_t)k * 128 + c0];
            wsT[c0 + 0][k] = f2bf(v.x);
            wsT[c0 + 1][k] = f2bf(v.y);
            wsT[c0 + 2][k] = f2bf(v.z);
            wsT[c0 + 3][k] = f2bf(v.w);
        }
    }
    const int lane = tid & 63;
    const int w = tid >> 6;
    const int ar = row0 + w * 16 + (lane & 15);  // A row (global)
    const int k0 = (lane >> 4) * 8;
    s16x8 afrag[4];
#pragma unroll
    for (int kk = 0; kk < 4; ++kk) {
        float4 va = *(const float4*)&x[(size_t)ar * 128 + kk * 32 + k0];
        float4 vb = *(const float4*)&x[(size_t)ar * 128 + kk * 32 + k0 + 4];
        u16x8 t;
        t[0] = f2bf(va.x); t[1] = f2bf(va.y); t[2] = f2bf(va.z); t[3] = f2bf(va.w);
        t[4] = f2bf(vb.x); t[5] = f2bf(vb.y); t[6] = f2bf(vb.z); t[7] = f2bf(vb.w);
        afrag[kk] = *(s16x8*)&t;
    }
    __syncthreads();
    f32x4 acc[8];
#pragma unroll
    for (int n = 0; n < 8; ++n) acc[n] = (f32x4){0.f, 0.f, 0.f, 0.f};
#pragma unroll
    for (int n = 0; n < 8; ++n) {
        const int bc = n * 16 + (lane & 15);
#pragma unroll
        for (int kk = 0; kk < 4; ++kk) {
            s16x8 bfrag = *(const s16x8*)&wsT[bc][kk * 32 + k0];
            acc[n] = __builtin_amdgcn_mfma_f32_16x16x32_bf16(afrag[kk], bfrag, acc[n], 0, 0, 0);
        }
    }
    const int orow = row0 + w * 16 + (lane >> 4) * 4;
    const float s0 = isd[orow + 0];
    const float s1 = isd[orow + 1];
    const float s2 = isd[orow + 2];
    const float s3 = isd[orow + 3];
#pragma unroll
    for (int n = 0; n < 8; ++n) {
        const int col = n * 16 + (lane & 15);
        t1s[(size_t)(orow + 0) * 128 + col] = f2bf(s0 * acc[n][0]);
        t1s[(size_t)(orow + 1) * 128 + col] = f2bf(s1 * acc[n][1]);
        t1s[(size_t)(orow + 2) * 128 + col] = f2bf(s2 * acc[n][2]);
        t1s[(size_t)(orow + 3) * 128 + col] = f2bf(s3 * acc[n][3]);
    }
}

// ============ FUSED layer-1 aggregate + relu + GEMM2, LDS-staged edge indices ============
// 16 consecutive nodes/block: their evw16 ranges are one contiguous chunk
__global__ __launch_bounds__(256) void fused_agg_gemm2(const int* __restrict__ row_start,
                                                       const int* __restrict__ deg,
                                                       const unsigned short* __restrict__ evw16,
                                                       const float* __restrict__ isd,
                                                       const unsigned short* __restrict__ src,
                                                       const float* __restrict__ W2,
                                                       float* __restrict__ t2s) {
    __shared__ unsigned short hs[16][136];   // bf16 h tile
    __shared__ float w2T[16][132];           // w2T[c][k] = W2[k][c]
    __shared__ unsigned short lidx[1024];    // staged edge indices (contiguous chunk)
    const int tid = threadIdx.x;
    const int n0 = blockIdx.x * 16;
    // stage edge indices for all 16 nodes (coalesced, contiguous within bucket)
    const int eb = row_start[n0];
    const int ee = row_start[n0 + 15] + deg[n0 + 15];
    const int cnt = ee - eb;
    for (int i = tid; i < cnt; i += 256) lidx[i] = evw16[eb + i];
    // stage W2^T
    for (int i = tid; i < 128 * 16; i += 256) {
        int k = i >> 4, cc = i & 15;
        w2T[cc][k] = W2[i];
    }
    const int slot = tid >> 4;
    const int node = n0 + slot;
    const int c0 = (tid & 15) * 8;
    const int rs = row_start[node];
    const int d = deg[node];
    const int ib = rs - eb;  // base into lidx
    const float s = isd[node];
    __syncthreads();
    float acc[8] = {};
    int p = 0;
    for (; p + 8 <= d; p += 8) {
        int v0 = lidx[ib + p + 0];
        int v1 = lidx[ib + p + 1];
        int v2 = lidx[ib + p + 2];
        int v3 = lidx[ib + p + 3];
        int v4 = lidx[ib + p + 4];
        int v5 = lidx[ib + p + 5];
        int v6 = lidx[ib + p + 6];
        int v7 = lidx[ib + p + 7];
        u16x8 a0 = *(const u16x8*)&src[(size_t)v0 * 128 + c0];
        u16x8 a1 = *(const u16x8*)&src[(size_t)v1 * 128 + c0];
        u16x8 a2 = *(const u16x8*)&src[(size_t)v2 * 128 + c0];
        u16x8 a3 = *(const u16x8*)&src[(size_t)v3 * 128 + c0];
        u16x8 a4 = *(const u16x8*)&src[(size_t)v4 * 128 + c0];
        u16x8 a5 = *(const u16x8*)&src[(size_t)v5 * 128 + c0];
        u16x8 a6 = *(const u16x8*)&src[(size_t)v6 * 128 + c0];
        u16x8 a7 = *(const u16x8*)&src[(size_t)v7 * 128 + c0];
#pragma unroll
        for (int j = 0; j < 8; ++j)
            acc[j] += ((b2f(a0[j]) + b2f(a1[j])) + (b2f(a2[j]) + b2f(a3[j]))) +
                      ((b2f(a4[j]) + b2f(a5[j])) + (b2f(a6[j]) + b2f(a7[j])));
    }
    for (; p + 2 <= d; p += 2) {
        int v0 = lidx[ib + p + 0];
        int v1 = lidx[ib + p + 1];
        u16x8 a0 = *(const u16x8*)&src[(size_t)v0 * 128 + c0];
        u16x8 a1 = *(const u16x8*)&src[(size_t)v1 * 128 + c0];
#pragma unroll
        for (int j = 0; j < 8; ++j) acc[j] += b2f(a0[j]) + b2f(a1[j]);
    }
    if (p < d) {
        int v0 = lidx[ib + p];
        u16x8 a = *(const u16x8*)&src[(size_t)v0 * 128 + c0];
#pragma unroll
        for (int j = 0; j < 8; ++j) acc[j] += b2f(a[j]);
    }
    u16x8 o;
#pragma unroll
    for (int j = 0; j < 8; ++j) o[j] = f2bf(fmaxf(s * acc[j], 0.f));
    *(u16x8*)&hs[slot][c0] = o;
    __syncthreads();
    // phase 2: thread (slot, tx) computes t2s[node][tx]
    const int tx = tid & 15;
    float acc2 = 0.f;
#pragma unroll
    for (int k = 0; k < 128; k += 8) {
        u16x8 hv = *(const u16x8*)&hs[slot][k];
#pragma unroll
        for (int j = 0; j < 8; ++j) acc2 += b2f(hv[j]) * w2T[tx][k + j];
    }
    t2s[(size_t)node * 16 + tx] = s * acc2;
}

// ============ gather F=16, LDS-staged edge indices (64 nodes/block) ============
__global__ __launch_bounds__(256) void spmm_gather16f(const int* __restrict__ row_start,
                                                      const int* __restrict__ deg,
                                                      const unsigned short* __restrict__ evw16,
                                                      const float* __restrict__ isd,
                                                      const float* __restrict__ t2s,
                                                      float* __restrict__ out) {
    __shared__ unsigned short lidx[2048];
    const int tid = threadIdx.x;
    const int n0 = blockIdx.x * 64;
    const int eb = row_start[n0];
    const int ee = row_start[n0 + 63] + deg[n0 + 63];
    const int cnt = ee - eb;
    for (int i = tid; i < cnt; i += 256) lidx[i] = evw16[eb + i];
    const int node = n0 + (tid >> 2);
    const int j = (tid & 3) * 4;
    const int rs = row_start[node];
    const int d = deg[node];
    const int ib = rs - eb;
    const float s = isd[node];
    __syncthreads();
    float4 acc = {0.f, 0.f, 0.f, 0.f};
    int p = 0;
    for (; p + 4 <= d; p += 4) {
        int v0 = lidx[ib + p + 0];
        int v1 = lidx[ib + p + 1];
        int v2 = lidx[ib + p + 2];
        int v3 = lidx[ib + p + 3];
        float4 a0 = *(const float4*)&t2s[(size_t)v0 * 16 + j];
        float4 a1 = *(const float4*)&t2s[(size_t)v1 * 16 + j];
        float4 a2 = *(const float4*)&t2s[(size_t)v2 * 16 + j];
        float4 a3 = *(const float4*)&t2s[(size_t)v3 * 16 + j];
        acc.x += (a0.x + a1.x) + (a2.x + a3.x);
        acc.y += (a0.y + a1.y) + (a2.y + a3.y);
        acc.z += (a0.z + a1.z) + (a2.z + a3.z);
        acc.w += (a0.w + a1.w) + (a2.w + a3.w);
    }
    for (; p < d; ++p) {
        int v = lidx[ib + p];
        float4 a = *(const float4*)&t2s[(size_t)v * 16 + j];
        acc.x += a.x;
        acc.y += a.y;
        acc.z += a.z;
        acc.w += a.w;
    }
    float4 o;
    o.x = s * acc.x;
    o.y = s * acc.y;
    o.z = s * acc.z;
    o.w = s * acc.w;
    *(float4*)&out[(size_t)node * 16 + j] = o;
}

extern "C" void kernel_launch(void* const* d_in, const int* in_sizes, int n_in,
                              void* d_out, int out_size, void* d_ws, size_t ws_size,
                              hipStream_t stream) {
    const float* x  = (const float*)d_in[0];
    const int*   eu = (const int*)d_in[1];
    const int*   ev = (const int*)d_in[2];
    // d_in[3] (edge_weight) unused: recomputed separably from degrees
    const float* W1 = (const float*)d_in[4];
    const float* W2 = (const float*)d_in[5];
    float* out = (float*)d_out;

    // workspace layout (16B-aligned carve-outs)
    char* p = (char*)d_ws;
    int* row_start        = (int*)p;            p += (size_t)NN * 4;            // 256KB
    int* deg              = (int*)p;            p += (size_t)NN * 4;            // 256KB
    float* isd            = (float*)p;          p += (size_t)NN * 4;            // 256KB
    int* cursors          = (int*)p;            p += 4096;                      // 1KB used
    unsigned int* tmp     = (unsigned int*)p;   p += (size_t)256 * BCAP * 4;    // 8MB
    unsigned short* evw16 = (unsigned short*)p; p += (size_t)256 * BCAP * 2;    // 4MB
    unsigned short* t1s   = (unsigned short*)p; p += (size_t)NN * FH * 2;       // 16MB
    float* t2s            = (float*)p;                                          // 4MB

    // CSR build: bucket partition into padded regions, then per-bucket sort
    init_kernel<<<1, 256, 0, stream>>>(cursors);
    bucketA<<<NE / EPB, 256, 0, stream>>>(eu, ev, cursors, tmp);
    bucketB<<<256, 256, 0, stream>>>(cursors, tmp, evw16, row_start, deg, isd);

    // layer 1: t1s = bf16(isd * (x @ W1))
    gemm1_mfma<<<NN / 64, 256, 0, stream>>>(x, W1, isd, t1s);

    // fused: h = relu(isd * gather(t1s)) ; t2s = isd * (h @ W2)
    fused_agg_gemm2<<<NN / 16, 256, 0, stream>>>(row_start, deg, evw16, isd, t1s, W2, t2s);

    // out = isd * gather(t2s)
    spmm_gather16f<<<NN / 64, 256, 0, stream>>>(row_start, deg, evw16, isd, t2s, out);
}